// Round 4
// baseline (124.421 us; speedup 1.0000x reference)
//
#include <hip/hip_runtime.h>
#include <hip/hip_bf16.h>

typedef __attribute__((ext_vector_type(8))) short bf16x8;
typedef __attribute__((ext_vector_type(4))) float floatx4;

#define NB 128
#define NT 256
#define NC 384
#define NH 8
#define ND 48

static __device__ __forceinline__ unsigned short f2bf(float f) {
  __hip_bfloat16 h = __float2bfloat16(f);
  return __builtin_bit_cast(unsigned short, h);
}

static __device__ __forceinline__ void gload16(const unsigned short* g, unsigned short* l) {
  __builtin_amdgcn_global_load_lds(
      (const __attribute__((address_space(1))) void*)g,
      (__attribute__((address_space(3))) void*)l, 16, 0, 0);
}

// ---------------- Prep: W_qkv -> per-head-permuted [8][144][384] bf16 (rows: q48|k48|v48),
//                  W_proj -> [384][384] bf16 transposed, x -> bf16.
__global__ __launch_bounds__(256) void k_prep(const float* __restrict__ x,
                                              const float* __restrict__ Wq,
                                              const float* __restrict__ Wp,
                                              unsigned short* __restrict__ xbf,
                                              unsigned short* __restrict__ Wq2,
                                              unsigned short* __restrict__ WpT) {
  const int blk = blockIdx.x;
  const int t = threadIdx.x;
  if (blk < 144) {
    __shared__ float T[64][65];
    const float* src;
    int N, kt, nt;
    if (blk < 108) { src = Wq; N = 1152; kt = blk / 18; nt = blk % 18; }
    else { int b2 = blk - 108; src = Wp; N = 384; kt = b2 / 6; nt = b2 % 6; }
    const int k0 = kt * 64, n0 = nt * 64;
    const int r = t >> 2, c = (t & 3) * 16;
    const float* s = src + (size_t)(k0 + r) * N + n0 + c;
#pragma unroll
    for (int i = 0; i < 4; ++i) *(float4*)&T[r][c + i * 4] = ((const float4*)s)[i];
    __syncthreads();
    unsigned short o[16];
#pragma unroll
    for (int i = 0; i < 16; ++i) o[i] = f2bf(T[c + i][r]);
    unsigned short* dp;
    if (blk < 108) {
      const int n = n0 + r;                       // 0..1151
      const int hg = (n % 384) / 48;
      const int comp = n / 384;
      const int d = n % 48;
      dp = Wq2 + (size_t)(hg * 144 + comp * 48 + d) * 384 + k0 + c;
    } else {
      dp = WpT + (size_t)(n0 + r) * 384 + k0 + c;
    }
    *(bf16x8*)dp = *(bf16x8*)&o[0];
    *(bf16x8*)(dp + 8) = *(bf16x8*)&o[8];
  } else {
    // x fp32 -> bf16, vec8 grid-stride
    const int n8 = (NB * NT * NC) / 8;            // 1,572,864
    int idx = (blk - 144) * 256 + t;
    const int stride = (gridDim.x - 144) * 256;
    for (; idx < n8; idx += stride) {
      const float* s = x + (size_t)idx * 8;
      float v[8];
      *(float4*)&v[0] = ((const float4*)s)[0];
      *(float4*)&v[4] = ((const float4*)s)[1];
      bf16x8 p;
#pragma unroll
      for (int i = 0; i < 8; ++i) p[i] = f2bf(v[i]);
      *(bf16x8*)(xbf + (size_t)idx * 8) = p;
    }
  }
}

// ---------------- Fused kernel: per (b, head-pair) compute QKV (GEMM) + windowed
// causal attention + gate, write attg bf16 [B][T][C]. QKV never touches HBM.
__global__ __launch_bounds__(512, 2) void k_qkattn(const unsigned short* __restrict__ xbf,
                                                   const unsigned short* __restrict__ Wq2,
                                                   const float* __restrict__ bq,
                                                   const float* __restrict__ gate,
                                                   unsigned short* __restrict__ attg) {
  // LDS layout (elems): staging 25600 (A dbuf 2*8192 | B dbuf 2*4608; P aliases A region)
  //                     Qs 256*72 | Ks 256*72 | Vt 48*280   => 148.25 KB total
  __shared__ __align__(16) unsigned short LDSU[25600 + 18432 + 18432 + 13440];
  unsigned short* Astg = LDSU;             // 2 x 8192
  unsigned short* Bstg = LDSU + 16384;     // 2 x 4608
  unsigned short* Qs = LDSU + 25600;       // [256][72], cols 48..63 zero
  unsigned short* Ks = Qs + 18432;         // [256][72], cols 48..63 zero
  unsigned short* Vt = Ks + 18432;         // [48][280], cols 256..279 zero

  const int t = threadIdx.x, lane = t & 63, w = t >> 6;
  const int lq = lane & 15, lg = lane >> 4;
  const int blk = blockIdx.x, b = blk >> 2, hp = blk & 3;
  const unsigned short* xb = xbf + (size_t)b * NT * NC;
  const float scale = 0.14433756729740643f;  // 1/sqrt(48)

  {  // one-time zero of pad regions (visible after in-loop barriers)
    bf16x8 z = {};
    {
      int row = t >> 1, c0 = 48 + (t & 1) * 8;
      *(bf16x8*)&Qs[row * 72 + c0] = z;
      *(bf16x8*)&Ks[row * 72 + c0] = z;
    }
    if (t < 144) {
      int row = t / 3, c0 = 256 + (t % 3) * 8;
      *(bf16x8*)&Vt[row * 280 + c0] = z;
    }
  }

#define STAGE_F(k0, buf)                                                            \
  {                                                                                 \
    {                                                                               \
      int r0 = w * 32 + (lane >> 2);                                                \
      int r1 = r0 + 16;                                                             \
      gload16(xb + (size_t)r0 * 384 + (k0) + 8 * ((lane & 3) ^ ((r0 >> 1) & 3)),    \
              Astg + (buf)*8192 + w * 1024);                                        \
      gload16(xb + (size_t)r1 * 384 + (k0) + 8 * ((lane & 3) ^ ((r1 >> 1) & 3)),    \
              Astg + (buf)*8192 + w * 1024 + 512);                                  \
    }                                                                               \
    if (w < 4) {                                                                    \
      int r0 = w * 32 + (lane >> 2);                                                \
      int r1 = r0 + 16;                                                             \
      gload16(Wh + (size_t)r0 * 384 + (k0) + 8 * ((lane & 3) ^ ((r0 >> 1) & 3)),    \
              Bstg + (buf)*4608 + w * 1024);                                        \
      gload16(Wh + (size_t)r1 * 384 + (k0) + 8 * ((lane & 3) ^ ((r1 >> 1) & 3)),    \
              Bstg + (buf)*4608 + w * 1024 + 512);                                  \
    } else if (w == 4) {                                                            \
      int r0 = 128 + (lane >> 2);                                                   \
      gload16(Wh + (size_t)r0 * 384 + (k0) + 8 * ((lane & 3) ^ ((r0 >> 1) & 3)),    \
              Bstg + (buf)*4608 + 4096);                                            \
    }                                                                               \
  }

  for (int h = 0; h < 2; ++h) {
    const int hg = hp * 2 + h;
    const unsigned short* Wh = Wq2 + (size_t)hg * 144 * 384;
    __syncthreads();  // staging region (aliased P) + Q/K/V safe to overwrite

    floatx4 acc[2][9] = {};
    STAGE_F(0, 0);
    __syncthreads();
    int cur = 0;
    for (int k0 = 0; k0 < 384; k0 += 32) {
      const int nk = k0 + 32;
      if (nk < 384) STAGE_F(nk, cur ^ 1);
      const unsigned short* Ac = Astg + cur * 8192;
      const unsigned short* Bc = Bstg + cur * 4608;
      bf16x8 afr[2], bfr[9];
#pragma unroll
      for (int mt = 0; mt < 2; ++mt) {
        const int R = w * 32 + mt * 16 + lq;
        afr[mt] = *(const bf16x8*)&Ac[R * 32 + 8 * (lg ^ ((R >> 1) & 3))];
      }
#pragma unroll
      for (int nt = 0; nt < 9; ++nt) {
        const int R = nt * 16 + lq;
        bfr[nt] = *(const bf16x8*)&Bc[R * 32 + 8 * (lg ^ ((R >> 1) & 3))];
      }
#pragma unroll
      for (int mt = 0; mt < 2; ++mt)
#pragma unroll
        for (int nt = 0; nt < 9; ++nt)
          acc[mt][nt] = __builtin_amdgcn_mfma_f32_16x16x32_bf16(afr[mt], bfr[nt], acc[mt][nt], 0, 0, 0);
      __syncthreads();
      cur ^= 1;
    }

    // epilogue: +bias; Q *= scale; scatter to Qs/Ks/Vt
#pragma unroll
    for (int nt = 0; nt < 9; ++nt) {
      const int comp = nt / 3;
      const int d = (nt % 3) * 16 + lq;
      const float bias = bq[comp * 384 + hg * 48 + d];
      if (comp == 0) {
#pragma unroll
        for (int mt = 0; mt < 2; ++mt)
#pragma unroll
          for (int j = 0; j < 4; ++j) {
            const int row = w * 32 + mt * 16 + lg * 4 + j;
            Qs[row * 72 + d] = f2bf((acc[mt][nt][j] + bias) * scale);
          }
      } else if (comp == 1) {
#pragma unroll
        for (int mt = 0; mt < 2; ++mt)
#pragma unroll
          for (int j = 0; j < 4; ++j) {
            const int row = w * 32 + mt * 16 + lg * 4 + j;
            Ks[row * 72 + d] = f2bf(acc[mt][nt][j] + bias);
          }
      } else {
#pragma unroll
        for (int mt = 0; mt < 2; ++mt) {
          unsigned short pk[4];
#pragma unroll
          for (int j = 0; j < 4; ++j) pk[j] = f2bf(acc[mt][nt][j] + bias);
          const int rowb = w * 32 + mt * 16 + lg * 4;
          *(uint2*)&Vt[d * 280 + rowb] = *(const uint2*)pk;
        }
      }
    }
    __syncthreads();  // Q/K/V visible to all waves

    // ---- attention: wave w handles queries [32w, 32w+32), two 16-q subtiles
    unsigned short* Pw = LDSU + w * 1664;  // per-wave P [16][104], aliases A-staging
#pragma unroll
    for (int s = 0; s < 2; ++s) {
      const int qs = w * 32 + s * 16;
      const int kstart = (qs >= 64) ? (qs - 64) : 0;

      const unsigned short* qrow = &Qs[(size_t)(qs + lq) * 72];
      bf16x8 aq0 = *(const bf16x8*)(qrow + lg * 8);
      bf16x8 aq1 = *(const bf16x8*)(qrow + 32 + lg * 8);  // cols 48..63 are zeros

      floatx4 sv4[5];
#pragma unroll
      for (int kt = 0; kt < 5; ++kt) {
        const int kr = kstart + kt * 16 + lq;
        bf16x8 kb0 = *(const bf16x8*)&Ks[kr * 72 + lg * 8];
        bf16x8 kb1 = *(const bf16x8*)&Ks[kr * 72 + 32 + lg * 8];
        floatx4 z = {};
        z = __builtin_amdgcn_mfma_f32_16x16x32_bf16(aq0, kb0, z, 0, 0, 0);
        z = __builtin_amdgcn_mfma_f32_16x16x32_bf16(aq1, kb1, z, 0, 0, 0);
        sv4[kt] = z;
      }

      floatx4 pj[5];
#pragma unroll
      for (int j = 0; j < 4; ++j) {
        const int qa = qs + lg * 4 + j;
        float mx = -1e30f;
        float sv[5];
        bool ok[5];
#pragma unroll
        for (int kt = 0; kt < 5; ++kt) {
          const int ka = kstart + kt * 16 + lq;
          sv[kt] = sv4[kt][j];
          ok[kt] = (ka <= qa) && (qa - ka <= 64);
          if (ok[kt]) mx = fmaxf(mx, sv[kt]);
        }
#pragma unroll
        for (int dd = 1; dd < 16; dd <<= 1) mx = fmaxf(mx, __shfl_xor(mx, dd));
        float sum = 0.f;
#pragma unroll
        for (int kt = 0; kt < 5; ++kt) {
          float p = ok[kt] ? __expf(sv[kt] - mx) : 0.f;
          pj[kt][j] = p;
          sum += p;
        }
#pragma unroll
        for (int dd = 1; dd < 16; dd <<= 1) sum += __shfl_xor(sum, dd);
        const float inv = 1.f / sum;
#pragma unroll
        for (int kt = 0; kt < 5; ++kt) pj[kt][j] *= inv;
      }

#pragma unroll
      for (int kt = 0; kt < 5; ++kt)
#pragma unroll
        for (int j = 0; j < 4; ++j)
          Pw[(lg * 4 + j) * 104 + kt * 16 + lq] = f2bf(pj[kt][j]);
#pragma unroll
      for (int j = 0; j < 4; ++j) Pw[lq * 104 + 80 + lg * 4 + j] = 0;

      floatx4 o[3] = {};
#pragma unroll
      for (int c = 0; c < 3; ++c) {
        bf16x8 ap = *(const bf16x8*)&Pw[lq * 104 + c * 32 + lg * 8];
#pragma unroll
        for (int nt = 0; nt < 3; ++nt) {
          bf16x8 av = *(const bf16x8*)&Vt[(nt * 16 + lq) * 280 + kstart + c * 32 + lg * 8];
          o[nt] = __builtin_amdgcn_mfma_f32_16x16x32_bf16(ap, av, o[nt], 0, 0, 0);
        }
      }
#pragma unroll
      for (int nt = 0; nt < 3; ++nt) {
        const int d = nt * 16 + lq;
        const int cg = hg * ND + d;
        const float g = gate[cg];
#pragma unroll
        for (int j = 0; j < 4; ++j) {
          const int tt = qs + lg * 4 + j;
          attg[((size_t)b * NT + tt) * NC + cg] = f2bf(o[nt][j] * g);
        }
      }
    }
  }
#undef STAGE_F
}

// ---------------- Kernel 3: out = attg @ WpT^T + b_proj (fp32 out), 2-phase dbuf
__global__ __launch_bounds__(256) void k_proj(const unsigned short* __restrict__ A,
                                              const unsigned short* __restrict__ WpT,
                                              const float* __restrict__ bp,
                                              float* __restrict__ out) {
  __shared__ __align__(16) unsigned short As[2 * 128 * 32];
  __shared__ __align__(16) unsigned short Bs[2 * 128 * 32];
  const int t = threadIdx.x, lane = t & 63, w = t >> 6;
  const int wm = w >> 1, wn = w & 1;
  const int lq = lane & 15, lg = lane >> 4;
  const int m0 = blockIdx.x * 128, n0 = blockIdx.y * 128;
  const unsigned short* Ag = A + (size_t)(m0 + w * 32 + (lane >> 2)) * 384 + (lane & 3) * 8;
  const unsigned short* Bg = WpT + (size_t)(n0 + w * 32 + (lane >> 2)) * 384 + (lane & 3) * 8;
  floatx4 acc[4][4] = {};

#define STAGE_P(k0, buf)                                                   \
  {                                                                        \
    gload16(Ag + (k0), As + (buf)*4096 + (w * 32) * 32);                   \
    gload16(Ag + (k0) + 16 * 384, As + (buf)*4096 + (w * 32 + 16) * 32);   \
    gload16(Bg + (k0), Bs + (buf)*4096 + (w * 32) * 32);                   \
    gload16(Bg + (k0) + 16 * 384, Bs + (buf)*4096 + (w * 32 + 16) * 32);   \
  }

  STAGE_P(0, 0);
  __syncthreads();

  int cur = 0;
  for (int k0 = 0; k0 < 384; k0 += 32) {
    const int nk = k0 + 32;
    if (nk < 384) STAGE_P(nk, cur ^ 1);
    const unsigned short* Ac = As + cur * 4096;
    const unsigned short* Bc = Bs + cur * 4096;
    bf16x8 a[4], b[4];
#pragma unroll
    for (int mt = 0; mt < 4; ++mt)
      a[mt] = *(const bf16x8*)&Ac[(wm * 64 + mt * 16 + lq) * 32 + lg * 8];
#pragma unroll
    for (int nt = 0; nt < 4; ++nt)
      b[nt] = *(const bf16x8*)&Bc[(wn * 64 + nt * 16 + lq) * 32 + lg * 8];
#pragma unroll
    for (int mt = 0; mt < 4; ++mt)
#pragma unroll
      for (int nt = 0; nt < 4; ++nt)
        acc[mt][nt] = __builtin_amdgcn_mfma_f32_16x16x32_bf16(a[mt], b[nt], acc[mt][nt], 0, 0, 0);
    __syncthreads();
    cur ^= 1;
  }
#pragma unroll
  for (int nt = 0; nt < 4; ++nt) {
    const int col = n0 + wn * 64 + nt * 16 + lq;
    const float bias = bp[col];
#pragma unroll
    for (int mt = 0; mt < 4; ++mt)
#pragma unroll
      for (int j = 0; j < 4; ++j) {
        const int row = m0 + wm * 64 + mt * 16 + lg * 4 + j;
        out[(size_t)row * 384 + col] = acc[mt][nt][j] + bias;
      }
  }
#undef STAGE_P
}

extern "C" void kernel_launch(void* const* d_in, const int* in_sizes, int n_in,
                              void* d_out, int out_size, void* d_ws, size_t ws_size,
                              hipStream_t stream) {
  const float* x    = (const float*)d_in[0];
  const float* Wq   = (const float*)d_in[1];
  const float* bq   = (const float*)d_in[2];
  const float* Wp   = (const float*)d_in[3];
  const float* bp   = (const float*)d_in[4];
  const float* gate = (const float*)d_in[5];

  const size_t nx = (size_t)NB * NT * NC;          // 12,582,912
  unsigned short* attg = (unsigned short*)d_ws;
  unsigned short* xbf  = attg + nx;
  unsigned short* Wq2  = xbf + nx;                 // [8][144][384]
  unsigned short* WpT  = Wq2 + (size_t)1152 * 384; // [384][384]
  float* out = (float*)d_out;

  k_prep<<<dim3(1680), 256, 0, stream>>>(x, Wq, Wp, xbf, Wq2, WpT);
  k_qkattn<<<dim3(512), 512, 0, stream>>>(xbf, Wq2, bq, gate, attg);
  k_proj<<<dim3(256, 3), 256, 0, stream>>>(attg, WpT, bp, out);
}

// Round 5
// 117.693 us; speedup vs baseline: 1.0572x; 1.0572x over previous
//
#include <hip/hip_runtime.h>
#include <hip/hip_bf16.h>

typedef __attribute__((ext_vector_type(8))) short bf16x8;
typedef __attribute__((ext_vector_type(4))) float floatx4;

#define NB 128
#define NT 256
#define NC 384
#define NH 8
#define ND 48

static __device__ __forceinline__ unsigned short f2bf(float f) {
  __hip_bfloat16 h = __float2bfloat16(f);
  return __builtin_bit_cast(unsigned short, h);
}

static __device__ __forceinline__ void gload16(const unsigned short* g, unsigned short* l) {
  __builtin_amdgcn_global_load_lds(
      (const __attribute__((address_space(1))) void*)g,
      (__attribute__((address_space(3))) void*)l, 16, 0, 0);
}

// ---------------- Prep (one launch): W_qkv^T -> [1152][384] bf16, W_proj^T -> [384][384] bf16,
//                  x fp32 -> bf16.
__global__ __launch_bounds__(256) void k_prep(const float* __restrict__ x,
                                              const float* __restrict__ Wq,
                                              const float* __restrict__ Wp,
                                              unsigned short* __restrict__ xbf,
                                              unsigned short* __restrict__ WqT,
                                              unsigned short* __restrict__ WpT) {
  const int blk = blockIdx.x;
  const int t = threadIdx.x;
  if (blk < 144) {
    __shared__ float T[64][65];
    const float* src;
    unsigned short* dst;
    int N, kt, nt;
    if (blk < 108) { src = Wq; dst = WqT; N = 1152; kt = blk / 18; nt = blk % 18; }
    else { int b2 = blk - 108; src = Wp; dst = WpT; N = 384; kt = b2 / 6; nt = b2 % 6; }
    const int k0 = kt * 64, n0 = nt * 64;
    const int r = t >> 2, c = (t & 3) * 16;
    const float* s = src + (size_t)(k0 + r) * N + n0 + c;
#pragma unroll
    for (int i = 0; i < 4; ++i) *(float4*)&T[r][c + i * 4] = ((const float4*)s)[i];
    __syncthreads();
    unsigned short o[16];
#pragma unroll
    for (int i = 0; i < 16; ++i) o[i] = f2bf(T[c + i][r]);
    unsigned short* dp = dst + (size_t)(n0 + r) * 384 + k0 + c;
    *(bf16x8*)dp = *(bf16x8*)&o[0];
    *(bf16x8*)(dp + 8) = *(bf16x8*)&o[8];
  } else {
    const int n8 = (NB * NT * NC) / 8;
    int idx = (blk - 144) * 256 + t;
    const int stride = (gridDim.x - 144) * 256;
    for (; idx < n8; idx += stride) {
      const float* s = x + (size_t)idx * 8;
      float v[8];
      *(float4*)&v[0] = ((const float4*)s)[0];
      *(float4*)&v[4] = ((const float4*)s)[1];
      bf16x8 p;
#pragma unroll
      for (int i = 0; i < 8; ++i) p[i] = f2bf(v[i]);
      *(bf16x8*)(xbf + (size_t)idx * 8) = p;
    }
  }
}

// ============ pipelined 128x128 GEMM body (3-deep, counted vmcnt, XOR-swizzled LDS) ====
// STAGE: thread covers rows w*32+(lane>>2), +16; source col XOR-swizzled, LDS linear.
#define STAGE_G(Ag, Bg, As, Bs, k0, buf)                                             \
  {                                                                                  \
    const int r0_ = (lane >> 2), sw0_ = 8 * ((lane & 3) ^ ((r0_ >> 1) & 3));         \
    const int r1_ = r0_ + 16,    sw1_ = 8 * ((lane & 3) ^ ((r1_ >> 1) & 3));         \
    gload16(Ag + (size_t)r0_ * 384 + (k0) + sw0_, As + (buf)*4096 + (w * 32) * 32);  \
    gload16(Ag + (size_t)r1_ * 384 + (k0) + sw1_, As + (buf)*4096 + (w * 32 + 16) * 32); \
    gload16(Bg + (size_t)r0_ * 384 + (k0) + sw0_, Bs + (buf)*4096 + (w * 32) * 32);  \
    gload16(Bg + (size_t)r1_ * 384 + (k0) + sw1_, Bs + (buf)*4096 + (w * 32 + 16) * 32); \
  }

#define GEMM_PIPE(Ag, Bg, As, Bs)                                                    \
  STAGE_G(Ag, Bg, As, Bs, 0, 0);                                                     \
  STAGE_G(Ag, Bg, As, Bs, 32, 1);                                                    \
  _Pragma("unroll") for (int t_ = 0; t_ < 12; ++t_) {                                \
    if (t_ < 11) asm volatile("s_waitcnt vmcnt(4)" ::: "memory");                    \
    else         asm volatile("s_waitcnt vmcnt(0)" ::: "memory");                    \
    __builtin_amdgcn_s_barrier();                                                    \
    if (t_ < 10) STAGE_G(Ag, Bg, As, Bs, (t_ + 2) * 32, (t_ + 2) % 3);               \
    const unsigned short* Ac_ = As + (t_ % 3) * 4096;                                \
    const unsigned short* Bc_ = Bs + (t_ % 3) * 4096;                                \
    bf16x8 a_[4], b_[4];                                                             \
    _Pragma("unroll") for (int mt = 0; mt < 4; ++mt) {                               \
      const int R = wm * 64 + mt * 16 + lq;                                          \
      a_[mt] = *(const bf16x8*)&Ac_[R * 32 + 8 * (lg ^ ((R >> 1) & 3))];             \
    }                                                                                \
    _Pragma("unroll") for (int nt = 0; nt < 4; ++nt) {                               \
      const int R = wn * 64 + nt * 16 + lq;                                          \
      b_[nt] = *(const bf16x8*)&Bc_[R * 32 + 8 * (lg ^ ((R >> 1) & 3))];             \
    }                                                                                \
    _Pragma("unroll") for (int mt = 0; mt < 4; ++mt)                                 \
      _Pragma("unroll") for (int nt = 0; nt < 4; ++nt)                               \
        acc[mt][nt] = __builtin_amdgcn_mfma_f32_16x16x32_bf16(a_[mt], b_[nt], acc[mt][nt], 0, 0, 0); \
  }

// ---------------- Kernel 1: qkv = xb @ WqT^T + b_qkv -> bf16 [3][B][H][T][48]
__global__ __launch_bounds__(256) void k_qkv(const unsigned short* __restrict__ xb,
                                             const unsigned short* __restrict__ WqT,
                                             const float* __restrict__ bq,
                                             unsigned short* __restrict__ qkv) {
  __shared__ __align__(16) unsigned short As[3 * 128 * 32];
  __shared__ __align__(16) unsigned short Bs[3 * 128 * 32];
  const int t = threadIdx.x, lane = t & 63, w = t >> 6;
  const int wm = w >> 1, wn = w & 1;
  const int lq = lane & 15, lg = lane >> 4;
  const int m0 = blockIdx.x * 128, n0 = blockIdx.y * 128;
  const unsigned short* Ag = xb + (size_t)(m0 + w * 32) * 384;
  const unsigned short* Bg = WqT + (size_t)(n0 + w * 32) * 384;
  floatx4 acc[4][4] = {};

  GEMM_PIPE(Ag, Bg, As, Bs);

  // epilogue: +bias, scatter to [comp][b][h][t][d] bf16
  const int comp = n0 / 384;
  const int cb = n0 - comp * 384;
#pragma unroll
  for (int nt = 0; nt < 4; ++nt) {
    const int cc = cb + wn * 64 + nt * 16 + lq;
    const int h = cc / 48, d = cc - h * 48;
    const float bias = bq[n0 + wn * 64 + nt * 16 + lq];
#pragma unroll
    for (int mt = 0; mt < 4; ++mt) {
#pragma unroll
      for (int j = 0; j < 4; ++j) {
        const int row = m0 + wm * 64 + mt * 16 + lg * 4 + j;
        const int bb = row >> 8, tt = row & 255;
        qkv[((((size_t)comp * NB + bb) * NH + h) * NT + tt) * ND + d] =
            f2bf(acc[mt][nt][j] + bias);
      }
    }
  }
}

// ---------------- Kernel 3: out = attg @ WpT^T + b_proj (fp32 out)
__global__ __launch_bounds__(256) void k_proj(const unsigned short* __restrict__ A,
                                              const unsigned short* __restrict__ WpT,
                                              const float* __restrict__ bp,
                                              float* __restrict__ out) {
  __shared__ __align__(16) unsigned short As[3 * 128 * 32];
  __shared__ __align__(16) unsigned short Bs[3 * 128 * 32];
  const int t = threadIdx.x, lane = t & 63, w = t >> 6;
  const int wm = w >> 1, wn = w & 1;
  const int lq = lane & 15, lg = lane >> 4;
  const int m0 = blockIdx.x * 128, n0 = blockIdx.y * 128;
  const unsigned short* Ag = A + (size_t)(m0 + w * 32) * 384;
  const unsigned short* Bg = WpT + (size_t)(n0 + w * 32) * 384;
  floatx4 acc[4][4] = {};

  GEMM_PIPE(Ag, Bg, As, Bs);

#pragma unroll
  for (int nt = 0; nt < 4; ++nt) {
    const int col = n0 + wn * 64 + nt * 16 + lq;
    const float bias = bp[col];
#pragma unroll
    for (int mt = 0; mt < 4; ++mt)
#pragma unroll
      for (int j = 0; j < 4; ++j) {
        const int row = m0 + wm * 64 + mt * 16 + lg * 4 + j;
        out[(size_t)row * 384 + col] = acc[mt][nt][j] + bias;
      }
  }
}

// ---------------- Kernel 2: windowed causal attention + gate, bf16 out [B][T][C]
__global__ __launch_bounds__(256) void k_attn(const unsigned short* __restrict__ qkv,
                                              const float* __restrict__ gate,
                                              unsigned short* __restrict__ attg) {
  __shared__ __align__(16) unsigned short Ks[128 * 72];      // [key][hd pad 64->72]
  __shared__ __align__(16) unsigned short Vt[48 * 152];      // [d][key pad 144->152]
  __shared__ __align__(16) unsigned short Ps[4 * 16 * 104];  // per-wave P [q][key pad]
  const int t = threadIdx.x;
  const int blk = blockIdx.x;
  const int tile = blk & 3;
  const int bh = blk >> 2;
  const int b = bh >> 3, h = bh & 7;
  const int base = tile * 64;
  const size_t kvoff = (size_t)bh * NT * ND;
  const unsigned short* qptr = qkv + kvoff;
  const unsigned short* kptr = qkv + (size_t)NB * NH * NT * ND + kvoff;
  const unsigned short* vptr = qkv + (size_t)2 * NB * NH * NT * ND + kvoff;

  if (t < 48) {
    bf16x8 z = {};
    *(bf16x8*)&Vt[t * 152 + 128] = z;
    *(bf16x8*)&Vt[t * 152 + 136] = z;
  }
  if (t < 128) {
    const int r = t, ka = base - 64 + r;
    unsigned short* dst = &Ks[r * 72];
    if (ka >= 0) {
      const unsigned short* src = kptr + (size_t)ka * ND;
#pragma unroll
      for (int i = 0; i < 6; ++i) *(bf16x8*)(dst + i * 8) = *(const bf16x8*)(src + i * 8);
      bf16x8 z = {};
      *(bf16x8*)(dst + 48) = z;
      *(bf16x8*)(dst + 56) = z;
    } else {
      bf16x8 z = {};
#pragma unroll
      for (int i = 0; i < 8; ++i) *(bf16x8*)(dst + i * 8) = z;
    }
  } else {
    const int r = t - 128, ka = base - 64 + r;
    if (ka >= 0) {
      const unsigned short* src = vptr + (size_t)ka * ND;
      bf16x8 vv[6];
#pragma unroll
      for (int i = 0; i < 6; ++i) vv[i] = *(const bf16x8*)(src + i * 8);
#pragma unroll
      for (int i = 0; i < 6; ++i)
#pragma unroll
        for (int j = 0; j < 8; ++j)
          Vt[(i * 8 + j) * 152 + r] = (unsigned short)vv[i][j];
    } else {
#pragma unroll
      for (int d = 0; d < 48; ++d) Vt[d * 152 + r] = 0;
    }
  }
  __syncthreads();

  const int lane = t & 63, w = t >> 6;
  const int lq = lane & 15, lg = lane >> 4;
  const int qs = base + w * 16;

  const unsigned short* qrow = qptr + (size_t)(qs + lq) * ND;
  bf16x8 aq0 = *(const bf16x8*)(qrow + lg * 8);
  bf16x8 aq1 = {};
  if (lg < 2) aq1 = *(const bf16x8*)(qrow + 32 + lg * 8);

  floatx4 s[5];
#pragma unroll
  for (int kt = 0; kt < 5; ++kt) {
    const unsigned short* kr = &Ks[(w * 16 + kt * 16 + lq) * 72];
    bf16x8 kb0 = *(const bf16x8*)(kr + lg * 8);
    bf16x8 kb1 = *(const bf16x8*)(kr + 32 + lg * 8);
    floatx4 z = {};
    z = __builtin_amdgcn_mfma_f32_16x16x32_bf16(aq0, kb0, z, 0, 0, 0);
    z = __builtin_amdgcn_mfma_f32_16x16x32_bf16(aq1, kb1, z, 0, 0, 0);
    s[kt] = z;
  }

  const float scale = 0.14433756729740643f;  // 1/sqrt(48)
  floatx4 pj[5];
#pragma unroll
  for (int j = 0; j < 4; ++j) {
    const int qa = qs + lg * 4 + j;
    float mx = -1e30f;
    float sv[5];
    bool ok[5];
#pragma unroll
    for (int kt = 0; kt < 5; ++kt) {
      const int ka = base - 64 + w * 16 + kt * 16 + lq;
      sv[kt] = s[kt][j] * scale;
      ok[kt] = (ka >= 0) && (ka <= qa) && (qa - ka <= 64);
      if (ok[kt]) mx = fmaxf(mx, sv[kt]);
    }
#pragma unroll
    for (int dd = 1; dd < 16; dd <<= 1) mx = fmaxf(mx, __shfl_xor(mx, dd));
    float sum = 0.f;
#pragma unroll
    for (int kt = 0; kt < 5; ++kt) {
      float p = ok[kt] ? __expf(sv[kt] - mx) : 0.f;
      pj[kt][j] = p;
      sum += p;
    }
#pragma unroll
    for (int dd = 1; dd < 16; dd <<= 1) sum += __shfl_xor(sum, dd);
    const float inv = 1.f / sum;
#pragma unroll
    for (int kt = 0; kt < 5; ++kt) pj[kt][j] *= inv;
  }

  unsigned short* pw = &Ps[w * 16 * 104];
#pragma unroll
  for (int kt = 0; kt < 5; ++kt)
#pragma unroll
    for (int j = 0; j < 4; ++j)
      pw[(lg * 4 + j) * 104 + kt * 16 + lq] = f2bf(pj[kt][j]);
#pragma unroll
  for (int j = 0; j < 4; ++j) pw[lq * 104 + 80 + lg * 4 + j] = 0;

  floatx4 o[3] = {};
#pragma unroll
  for (int c = 0; c < 3; ++c) {
    bf16x8 ap = *(const bf16x8*)&pw[lq * 104 + c * 32 + lg * 8];
#pragma unroll
    for (int nt = 0; nt < 3; ++nt) {
      bf16x8 av = *(const bf16x8*)&Vt[(nt * 16 + lq) * 152 + w * 16 + c * 32 + lg * 8];
      o[nt] = __builtin_amdgcn_mfma_f32_16x16x32_bf16(ap, av, o[nt], 0, 0, 0);
    }
  }
#pragma unroll
  for (int nt = 0; nt < 3; ++nt) {
    const int d = nt * 16 + lq;
    const int c = h * ND + d;
    const float g = gate[c];
#pragma unroll
    for (int j = 0; j < 4; ++j) {
      const int tt = qs + lg * 4 + j;
      attg[((size_t)b * NT + tt) * NC + c] = f2bf(o[nt][j] * g);
    }
  }
}

extern "C" void kernel_launch(void* const* d_in, const int* in_sizes, int n_in,
                              void* d_out, int out_size, void* d_ws, size_t ws_size,
                              hipStream_t stream) {
  const float* x    = (const float*)d_in[0];
  const float* Wq   = (const float*)d_in[1];
  const float* bq   = (const float*)d_in[2];
  const float* Wp   = (const float*)d_in[3];
  const float* bp   = (const float*)d_in[4];
  const float* gate = (const float*)d_in[5];

  const size_t nx = (size_t)NB * NT * NC;                // 12,582,912
  unsigned short* attg = (unsigned short*)d_ws;
  unsigned short* xbf  = attg + nx;
  unsigned short* qkvp = xbf + nx;
  unsigned short* WqT  = qkvp + (size_t)3 * NB * NH * NT * ND;
  unsigned short* WpT  = WqT + (size_t)384 * 1152;
  float* out = (float*)d_out;

  k_prep<<<dim3(1680), 256, 0, stream>>>(x, Wq, Wp, xbf, WqT, WpT);
  k_qkv<<<dim3(256, 9), 256, 0, stream>>>(xbf, WqT, bq, qkvp);
  k_attn<<<dim3(4096), 256, 0, stream>>>(qkvp, gate, attg);
  k_proj<<<dim3(256, 3), 256, 0, stream>>>(attg, WpT, bp, out);
}